// Round 1
// baseline (8766.042 us; speedup 1.0000x reference)
//
#include <hip/hip_runtime.h>

typedef unsigned short u16;
typedef __bf16 bf16x8 __attribute__((ext_vector_type(8)));
typedef float f32x4 __attribute__((ext_vector_type(4)));

#define N_NODES 100000
#define D 256
#define NLAYER 4
#define E2N 300000
#define E3N 200000
#define TGT 2000

__device__ __forceinline__ u16 f2b(float f) {
    union { float f; unsigned u; } v; v.f = f;
    unsigned r = v.u + 0x7FFFu + ((v.u >> 16) & 1u);
    return (u16)(r >> 16);
}
__device__ __forceinline__ float b2f(u16 u) {
    union { unsigned u; float f; } v; v.u = ((unsigned)u) << 16; return v.f;
}

// ---------------- embedding gather: h_bf16[i,:] = bf16(emb[x[i],:]) ----------------
__global__ __launch_bounds__(256)
void embed_kernel(const int* __restrict__ x, const float* __restrict__ emb,
                  u16* __restrict__ hb, int n) {
    int wid = threadIdx.x >> 6, lane = threadIdx.x & 63;
    int row = blockIdx.x * 4 + wid;
    if (row >= n) return;
    int v = x[row];
    float4 f = *(const float4*)(emb + v * D + lane * 4);
    ushort4 o; o.x = f2b(f.x); o.y = f2b(f.y); o.z = f2b(f.z); o.w = f2b(f.w);
    *(ushort4*)(hb + row * D + lane * 4) = o;
}

// ---------------- W (L,K,N) f32 -> Wt (L,N,K) bf16 ----------------
__global__ __launch_bounds__(256)
void convert_wt(const float* __restrict__ W, u16* __restrict__ Wt,
                int total, int K, int N) {
    int idx = blockIdx.x * 256 + threadIdx.x;
    if (idx >= total) return;
    int kk = idx % K;
    int rem = idx / K;
    int nn = rem % N;
    int l  = rem / N;
    Wt[idx] = f2b(W[(l * K + kk) * N + nn]);
}

// ---------------- fused gather-GEMM-scatter ----------------
// ARITY==0: root transform, A row m = node m, direct store to agg.
// ARITY==2/3: A[e,k] = hb[idx[k/256][e]][k%256]; atomicAdd C[e,n] into
//             agg[idx[n/256][e]][n%256].
#define BM 128
#define BN 128
#define BK 64
#define LDSP 144         // 64 bf16 + 8 pad = 144 B pitch (conflict-free reads)
#define BOFF 18432       // 128*144

template<int ARITY>
__global__ __launch_bounds__(256)
void gemm_scatter(const u16* __restrict__ hb, const u16* __restrict__ Wt,
                  const int* __restrict__ eidx, float* __restrict__ agg,
                  int E, int Ntiles) {
    constexpr int KT = (ARITY == 0 ? 1 : ARITY) * 256;
    __shared__ __align__(16) char smem[2 * 128 * LDSP];

    const int bid = blockIdx.x;
    const int mt = bid / Ntiles;
    const int nt = bid % Ntiles;
    const int m0 = mt * BM;
    const int tid = threadIdx.x;
    const int lane = tid & 63;
    const int wid = tid >> 6;
    const int wm = (wid >> 1) * 64;
    const int wn = (wid & 1) * 64;
    const int srow = tid >> 3;   // 0..31
    const int sk8  = tid & 7;    // 16B chunk within 128B row

    f32x4 acc[4][4];
#pragma unroll
    for (int i = 0; i < 4; ++i)
#pragma unroll
        for (int j = 0; j < 4; ++j)
            acc[i][j] = f32x4{0.f, 0.f, 0.f, 0.f};

    uint4 ra[4], rb[4];
    auto load_tile = [&](int k0) {
        const int slot_k = k0 >> 8;
        const int kin = k0 & 255;
#pragma unroll
        for (int i = 0; i < 4; ++i) {
            int row = i * 32 + srow;
            int e = m0 + row; e = (e < E) ? e : (E - 1);
            int node;
            if constexpr (ARITY == 0) node = e;
            else node = eidx[slot_k * E + e];
            ra[i] = *(const uint4*)(hb + node * D + kin + sk8 * 8);
            rb[i] = *(const uint4*)(Wt + (nt * BN + row) * KT + k0 + sk8 * 8);
        }
    };

    load_tile(0);
    for (int k0 = 0; k0 < KT; k0 += BK) {
        __syncthreads();   // previous tile's reads done
#pragma unroll
        for (int i = 0; i < 4; ++i) {
            int row = i * 32 + srow;
            *(uint4*)(smem + row * LDSP + sk8 * 16) = ra[i];
            *(uint4*)(smem + BOFF + row * LDSP + sk8 * 16) = rb[i];
        }
        __syncthreads();
        if (k0 + BK < KT) load_tile(k0 + BK);   // prefetch overlaps compute
#pragma unroll
        for (int ks = 0; ks < 2; ++ks) {
            const int koff = ks * 64 + (lane >> 4) * 16;
            bf16x8 af[4], bf[4];
#pragma unroll
            for (int mi = 0; mi < 4; ++mi)
                af[mi] = *(const bf16x8*)(smem + (wm + mi * 16 + (lane & 15)) * LDSP + koff);
#pragma unroll
            for (int ni = 0; ni < 4; ++ni)
                bf[ni] = *(const bf16x8*)(smem + BOFF + (wn + ni * 16 + (lane & 15)) * LDSP + koff);
#pragma unroll
            for (int mi = 0; mi < 4; ++mi)
#pragma unroll
                for (int ni = 0; ni < 4; ++ni)
                    acc[mi][ni] = __builtin_amdgcn_mfma_f32_16x16x32_bf16(
                        af[mi], bf[ni], acc[mi][ni], 0, 0, 0);
        }
    }

    // epilogue: C[row][col]; col = lane&15 (+ni*16), row = (lane>>4)*4+r (+mi*16)
    const int slot_n = (nt * BN) >> 8;
#pragma unroll
    for (int mi = 0; mi < 4; ++mi) {
#pragma unroll
        for (int r = 0; r < 4; ++r) {
            int row = m0 + wm + mi * 16 + ((lane >> 4) << 2) + r;
            if (row < E) {
                int base;
                if constexpr (ARITY == 0) base = row * D;
                else base = eidx[slot_n * E + row] * D;
#pragma unroll
                for (int ni = 0; ni < 4; ++ni) {
                    int col = (nt * BN + wn + ni * 16 + (lane & 15)) & (D - 1);
                    float v = acc[mi][ni][r];
                    if constexpr (ARITY == 0) agg[base + col] = v;
                    else atomicAdd(agg + base + col, v);
                }
            }
        }
    }
}

// ---------------- h = LN(relu(agg)) -> bf16 ----------------
__global__ __launch_bounds__(256)
void relu_ln_kernel(const float* __restrict__ agg, const float* __restrict__ g,
                    const float* __restrict__ b, u16* __restrict__ hb, int n) {
    int wid = threadIdx.x >> 6, lane = threadIdx.x & 63;
    int row = blockIdx.x * 4 + wid;
    if (row >= n) return;
    float4 v = *(const float4*)(agg + row * D + lane * 4);
    v.x = fmaxf(v.x, 0.f); v.y = fmaxf(v.y, 0.f);
    v.z = fmaxf(v.z, 0.f); v.w = fmaxf(v.w, 0.f);
    float s  = v.x + v.y + v.z + v.w;
    float s2 = v.x * v.x + v.y * v.y + v.z * v.z + v.w * v.w;
#pragma unroll
    for (int off = 1; off < 64; off <<= 1) {
        s  += __shfl_xor(s, off);
        s2 += __shfl_xor(s2, off);
    }
    float mu = s * 0.00390625f;
    float var = s2 * 0.00390625f - mu * mu;
    float rs = rsqrtf(var + 1e-5f);
    float4 gg = *(const float4*)(g + lane * 4);
    float4 bb = *(const float4*)(b + lane * 4);
    ushort4 o;
    o.x = f2b((v.x - mu) * rs * gg.x + bb.x);
    o.y = f2b((v.y - mu) * rs * gg.y + bb.y);
    o.z = f2b((v.z - mu) * rs * gg.z + bb.z);
    o.w = f2b((v.w - mu) * rs * gg.w + bb.w);
    *(ushort4*)(hb + row * D + lane * 4) = o;
}

// ---------------- head: out[t,:] = relu(LN(in[t,:] @ W + b)) ----------------
__global__ __launch_bounds__(256)
void head_layer(const u16* __restrict__ hb, const int* __restrict__ tgt,
                const float* __restrict__ inf,
                const float* __restrict__ W, const float* __restrict__ bias,
                const float* __restrict__ g, const float* __restrict__ beta,
                float* __restrict__ out, int gather) {
    __shared__ float xr[256];
    __shared__ float sm1[4], sm2[4];
    int t = blockIdx.x, tid = threadIdx.x;
    if (gather) { int node = tgt[t]; xr[tid] = b2f(hb[node * D + tid]); }
    else        { xr[tid] = inf[t * D + tid]; }
    __syncthreads();
    float a = bias[tid];
#pragma unroll 8
    for (int k = 0; k < 256; ++k) a = fmaf(xr[k], W[k * 256 + tid], a);
    float s = a, s2 = a * a;
#pragma unroll
    for (int off = 1; off < 64; off <<= 1) {
        s  += __shfl_xor(s, off);
        s2 += __shfl_xor(s2, off);
    }
    int wid = tid >> 6, lane = tid & 63;
    if (lane == 0) { sm1[wid] = s; sm2[wid] = s2; }
    __syncthreads();
    s  = sm1[0] + sm1[1] + sm1[2] + sm1[3];
    s2 = sm2[0] + sm2[1] + sm2[2] + sm2[3];
    float mu = s * 0.00390625f;
    float var = s2 * 0.00390625f - mu * mu;
    float rs = rsqrtf(var + 1e-5f);
    float y = (a - mu) * rs * g[tid] + beta[tid];
    out[t * 256 + tid] = fmaxf(y, 0.f);
}

// ---------------- final logit: out[t] = in[t,:] @ out_W + out_b ----------------
__global__ __launch_bounds__(256)
void head_out(const float* __restrict__ in, const float* __restrict__ ow,
              const float* __restrict__ ob, float* __restrict__ out, int T) {
    int wid = threadIdx.x >> 6, lane = threadIdx.x & 63;
    int t = blockIdx.x * 4 + wid;
    if (t >= T) return;
    float4 v = *(const float4*)(in + t * D + lane * 4);
    float4 w = *(const float4*)(ow + lane * 4);
    float s = v.x * w.x + v.y * w.y + v.z * w.z + v.w * w.w;
#pragma unroll
    for (int off = 1; off < 64; off <<= 1) s += __shfl_xor(s, off);
    if (lane == 0) out[t] = s + ob[0];
}

extern "C" void kernel_launch(void* const* d_in, const int* in_sizes, int n_in,
                              void* d_out, int out_size, void* d_ws, size_t ws_size,
                              hipStream_t stream) {
    (void)in_sizes; (void)n_in; (void)out_size; (void)ws_size;
    const int*   x      = (const int*)d_in[0];
    // d_in[1] = edge_index (unused by reference)
    const int*   e2     = (const int*)d_in[2];
    const int*   e3     = (const int*)d_in[3];
    const int*   tgt    = (const int*)d_in[4];
    const float* emb    = (const float*)d_in[5];
    const float* W_root = (const float*)d_in[6];
    const float* W_e2   = (const float*)d_in[7];
    const float* W_e3   = (const float*)d_in[8];
    const float* ln_g   = (const float*)d_in[9];
    const float* ln_b   = (const float*)d_in[10];
    const float* reg_W  = (const float*)d_in[11];
    const float* reg_b  = (const float*)d_in[12];
    const float* rln_g  = (const float*)d_in[13];
    const float* rln_b  = (const float*)d_in[14];
    const float* out_W  = (const float*)d_in[15];
    const float* out_b  = (const float*)d_in[16];
    float* out = (float*)d_out;

    char* ws = (char*)d_ws;
    float* agg = (float*)(ws);                        // 102,400,000 B
    u16*   hb  = (u16*)  (ws + 102400000);            //  51,200,000 B
    u16*   Wr  = (u16*)  (ws + 153600000);            //     524,288 B
    u16*   W2  = (u16*)  (ws + 154124288);            //   2,097,152 B
    u16*   W3  = (u16*)  (ws + 156221440);            //   4,718,592 B
    float* t0  = (float*)(ws + 160940032);            //   2,048,000 B
    float* t1  = (float*)(ws + 162988032);            //   2,048,000 B

    embed_kernel<<<N_NODES / 4, 256, 0, stream>>>(x, emb, hb, N_NODES);
    convert_wt<<<(NLAYER * 256 * 256 + 255) / 256, 256, 0, stream>>>(W_root, Wr, NLAYER * 256 * 256, 256, 256);
    convert_wt<<<(NLAYER * 512 * 512 + 255) / 256, 256, 0, stream>>>(W_e2, W2, NLAYER * 512 * 512, 512, 512);
    convert_wt<<<(NLAYER * 768 * 768 + 255) / 256, 256, 0, stream>>>(W_e3, W3, NLAYER * 768 * 768, 768, 768);

    const int mtR = (N_NODES + BM - 1) / BM;   // 782
    const int mt2 = (E2N + BM - 1) / BM;       // 2344
    const int mt3 = (E3N + BM - 1) / BM;       // 1563
    for (int l = 0; l < NLAYER; ++l) {
        gemm_scatter<0><<<mtR * 2, 256, 0, stream>>>(hb, Wr + (size_t)l * 256 * 256, nullptr, agg, N_NODES, 2);
        gemm_scatter<2><<<mt2 * 4, 256, 0, stream>>>(hb, W2 + (size_t)l * 512 * 512, e2, agg, E2N, 4);
        gemm_scatter<3><<<mt3 * 6, 256, 0, stream>>>(hb, W3 + (size_t)l * 768 * 768, e3, agg, E3N, 6);
        relu_ln_kernel<<<N_NODES / 4, 256, 0, stream>>>(agg, ln_g + l * D, ln_b + l * D, hb, N_NODES);
    }

    head_layer<<<TGT, 256, 0, stream>>>(hb, tgt, nullptr, reg_W, reg_b, rln_g, rln_b, t0, 1);
    head_layer<<<TGT, 256, 0, stream>>>(nullptr, nullptr, t0, reg_W + 65536, reg_b + 256, rln_g + 256, rln_b + 256, t1, 0);
    head_out<<<(TGT + 3) / 4, 256, 0, stream>>>(t1, out_W, out_b, out, TGT);
}